// Round 20
// baseline (232.584 us; speedup 1.0000x reference)
//
#include <hip/hip_runtime.h>
#include <math.h>

typedef __attribute__((ext_vector_type(4))) float f32x4;
typedef __attribute__((ext_vector_type(8))) short bf16x8;

// Problem constants
#define NB 16
#define NT 2048
#define NMEL 80
#define NPOS 512          // stacked positions per batch
#define EDIM 16
#define NEMB 8192
#define ENCD 512
#define MROWS (NB*511)    // 8176 logit rows
#define MPAD 8192
#define NVT 64            // 8192 / 128 col tiles

__device__ __forceinline__ unsigned short f2bf(float x) {
    union { float f; unsigned u; } v; v.f = x;
    unsigned r = v.u + 0x7fffu + ((v.u >> 16) & 1u);
    return (unsigned short)(r >> 16);
}

__device__ __forceinline__ void gl_lds16(const void* gsrc, void* lds) {
    __builtin_amdgcn_global_load_lds(
        (const __attribute__((address_space(1))) unsigned int*)gsrc,
        (__attribute__((address_space(3))) unsigned int*)lds,
        16, 0, 0);
}

// 4-way chunk-merge of the codes partials for one position (ascending chunk = ascending idx)
__device__ __forceinline__ int merge_code(const float* __restrict__ pscore,
                                          const int* __restrict__ pcidx, int g)
{
    float m = INFINITY; int mi = 0x7fffffff;
    #pragma unroll
    for (int c = 0; c < 4; ++c) {
        const float s = pscore[c * MPAD + g];
        const int  ix = pcidx [c * MPAD + g];
        if (s < m || (s == m && ix < mi)) { m = s; mi = ix; }
    }
    return mi;
}

// ---------------- Kernel 1: prep ----------------
// blocks 0..511   : LN+proj+normalize -> ynB bf16 [8192][32] (K-padded); zero presence/sctrl
// blocks 512..1023: enc->fp8
// blocks 1024..2047: tno->fp8 transpose x16
// blocks 2048..2079: emb -> embB bf16 [8192][32] (K-padded) + h2 f32 (exact)
__global__ __launch_bounds__(256) void prep_kernel(
    const float* __restrict__ feats, const float* __restrict__ proj,
    const float* __restrict__ emb, const float* __restrict__ enc,
    const float* __restrict__ tno,
    unsigned short* __restrict__ ynB, unsigned short* __restrict__ embB,
    float* __restrict__ h2, int* __restrict__ presence, int* __restrict__ sctrl,
    unsigned char* __restrict__ encF8, unsigned char* __restrict__ tnoF8)
{
    __shared__ float tileT[32][33];         // tno transpose staging
    const int bid = blockIdx.x;
    const int tid = threadIdx.x;

    if (bid < 512) {
        // ---- LN path: 16 positions per block, 4 per wave ----
        const int lane = tid & 63;
        const int wave = tid >> 6;
        const int gbase = bid * 16 + wave * 4;
        if (bid < 32) presence[bid * 256 + tid] = 0;
        if (bid == 32 && tid < 160) sctrl[tid] = 0;   // ticket + partials

        float yn[4][EDIM];
        #pragma unroll
        for (int pi = 0; pi < 4; ++pi) {
            const int g = gbase + pi;
            const int b = g >> 9;
            const int i = g & 511;
            float xv[5];
            float s = 0.f, sq = 0.f;
            #pragma unroll
            for (int qq = 0; qq < 5; ++qq) {
                const int d = lane + 64 * qq;
                const int j = d / 80, k = d - j * 80;
                const float v = feats[((b * NT) + (i * 4 + j)) * NMEL + k];
                xv[qq] = v; s += v; sq += v * v;
            }
            for (int m = 1; m < 64; m <<= 1) { s += __shfl_xor(s, m); sq += __shfl_xor(sq, m); }
            const float mean = s * (1.0f / 320.0f);
            const float var  = sq * (1.0f / 320.0f) - mean * mean;
            const float rstd = rsqrtf(var + 1e-6f);
            float acc[EDIM];
            #pragma unroll
            for (int e = 0; e < EDIM; ++e) acc[e] = 0.f;
            #pragma unroll
            for (int qq = 0; qq < 5; ++qq) {
                const int d = lane + 64 * qq;
                const float xn = (xv[qq] - mean) * rstd;
                #pragma unroll
                for (int e = 0; e < EDIM; ++e) acc[e] += xn * proj[d * EDIM + e];
            }
            for (int m = 1; m < 64; m <<= 1) {
                #pragma unroll
                for (int e = 0; e < EDIM; ++e) acc[e] += __shfl_xor(acc[e], m);
            }
            float nsq = 0.f;
            #pragma unroll
            for (int e = 0; e < EDIM; ++e) nsq += acc[e] * acc[e];
            const float inv = 1.0f / (sqrtf(nsq) + 1e-8f);
            #pragma unroll
            for (int e = 0; e < EDIM; ++e) yn[pi][e] = acc[e] * inv;
        }
        // all lanes hold the full yn after butterfly; lanes 0..3 write their position
        #pragma unroll
        for (int pi = 0; pi < 4; ++pi) {
            if (lane == pi) {
                unsigned short* dst = &ynB[(size_t)(gbase + pi) * 32];
                #pragma unroll
                for (int e = 0; e < EDIM; ++e) dst[e] = f2bf(yn[pi][e]);
                #pragma unroll
                for (int e = EDIM; e < 32; ++e) dst[e] = 0;
            }
        }
    } else if (bid < 1024) {
        // ---- enc f32 -> encF8 e4m3 [8192][512] bytes, padded rows zero ----
        const int bid2 = bid - 512;          // 0..511 -> 16 rows each
        const int lane = tid & 63;
        #pragma unroll
        for (int pass = 0; pass < 4; ++pass) {
            const int m = bid2 * 16 + pass * 4 + (tid >> 6);
            const int d = lane * 8;
            uint2 o = make_uint2(0u, 0u);
            if (m < MROWS) {
                const int b = m / 511, t = m - b * 511;
                const float4 f0 = *(const float4*)&enc[((size_t)(b * 512 + t)) * ENCD + d];
                const float4 f1 = *(const float4*)&enc[((size_t)(b * 512 + t)) * ENCD + d + 4];
                int w0 = __builtin_amdgcn_cvt_pk_fp8_f32(f0.x, f0.y, 0, false);
                w0     = __builtin_amdgcn_cvt_pk_fp8_f32(f0.z, f0.w, w0, true);
                int w1 = __builtin_amdgcn_cvt_pk_fp8_f32(f1.x, f1.y, 0, false);
                w1     = __builtin_amdgcn_cvt_pk_fp8_f32(f1.z, f1.w, w1, true);
                o.x = (unsigned)w0; o.y = (unsigned)w1;
            }
            *(uint2*)&encF8[(size_t)m * ENCD + d] = o;
        }
    } else if (bid < 2048) {
        // ---- tno f32 [512][8192] -> tnoF8 e4m3 [8192][512] bytes, scaled x16 ----
        const int bid2 = bid - 1024;         // 0..1023 -> 4 tiles each
        const int tx = tid & 31, ty = tid >> 5;   // 32 x 8 loaders
        const int np = tid >> 3, kc = tid & 7;    // 32 n-rows x 8 k-quads writers
        #pragma unroll
        for (int it = 0; it < 4; ++it) {
            const int tile = bid2 * 4 + it;       // 0..4095
            const int n0 = (tile & 255) * 32;
            const int k0 = (tile >> 8) * 32;
            __syncthreads();
            #pragma unroll
            for (int i = 0; i < 4; ++i)
                tileT[ty + 8 * i][tx] = tno[(size_t)(k0 + ty + 8 * i) * NEMB + n0 + tx];
            __syncthreads();
            const float t0 = 16.0f * tileT[kc * 4 + 0][np];
            const float t1 = 16.0f * tileT[kc * 4 + 1][np];
            const float t2 = 16.0f * tileT[kc * 4 + 2][np];
            const float t3 = 16.0f * tileT[kc * 4 + 3][np];
            int w = __builtin_amdgcn_cvt_pk_fp8_f32(t0, t1, 0, false);
            w     = __builtin_amdgcn_cvt_pk_fp8_f32(t2, t3, w, true);
            ((unsigned*)tnoF8)[(size_t)(n0 + np) * (ENCD / 4) + (k0 >> 2) + kc] = (unsigned)w;
        }
    } else {
        // ---- emb f32 [8192][16] -> embB bf16 [8192][32] (K-pad zeros) + h2 exact ----
        const int row = (bid - 2048) * 256 + tid;   // one row per thread
        const float* ep = &emb[(size_t)row * EDIM];
        const float4 e0 = *(const float4*)&ep[0];
        const float4 e1 = *(const float4*)&ep[4];
        const float4 e2v = *(const float4*)&ep[8];
        const float4 e3 = *(const float4*)&ep[12];
        const float e2 = e0.x*e0.x + e0.y*e0.y + e0.z*e0.z + e0.w*e0.w
                       + e1.x*e1.x + e1.y*e1.y + e1.z*e1.z + e1.w*e1.w
                       + e2v.x*e2v.x + e2v.y*e2v.y + e2v.z*e2v.z + e2v.w*e2v.w
                       + e3.x*e3.x + e3.y*e3.y + e3.z*e3.z + e3.w*e3.w;
        h2[row] = 0.5f * e2;
        unsigned short* dst = &embB[(size_t)row * 32];
        dst[0]  = f2bf(e0.x); dst[1]  = f2bf(e0.y); dst[2]  = f2bf(e0.z); dst[3]  = f2bf(e0.w);
        dst[4]  = f2bf(e1.x); dst[5]  = f2bf(e1.y); dst[6]  = f2bf(e1.z); dst[7]  = f2bf(e1.w);
        dst[8]  = f2bf(e2v.x); dst[9]  = f2bf(e2v.y); dst[10] = f2bf(e2v.z); dst[11] = f2bf(e2v.w);
        dst[12] = f2bf(e3.x); dst[13] = f2bf(e3.y); dst[14] = f2bf(e3.z); dst[15] = f2bf(e3.w);
        #pragma unroll
        for (int e = EDIM; e < 32; ++e) dst[e] = 0;
    }
}

// ---------------- Kernel 1b: MFMA argmin scan (pos-group x emb-chunk partials) ----------------
__global__ __launch_bounds__(256) void codes_mfma(
    const unsigned short* __restrict__ ynB, const unsigned short* __restrict__ embB,
    const float* __restrict__ h2,
    float* __restrict__ pscore, int* __restrict__ pcidx)
{
    const int tid = threadIdx.x;
    const int lane = tid & 63;
    const int wave = tid >> 6;
    const int pgrp  = blockIdx.x >> 2;   // 0..127 -> 64 positions
    const int chunk = blockIdx.x & 3;    // 0..3 -> 2048 embeddings
    const int p0 = pgrp * 64 + wave * 16;
    const int l15 = lane & 15, q = lane >> 4;

    const bf16x8 a = *(const bf16x8*)&ynB[(size_t)(p0 + l15) * 32 + q * 8];

    float mn[4]; int mi[4];
    #pragma unroll
    for (int r = 0; r < 4; ++r) { mn[r] = INFINITY; mi[r] = 0x7fffffff; }

    const int e0 = chunk * 2048;
    #pragma unroll 4
    for (int g = 0; g < 128; ++g) {
        const int eidx = e0 + g * 16 + l15;
        const bf16x8 b = *(const bf16x8*)&embB[(size_t)eidx * 32 + q * 8];
        const float hv = h2[eidx];
        f32x4 d = __builtin_amdgcn_mfma_f32_16x16x32_bf16(a, b, (f32x4){0.f, 0.f, 0.f, 0.f}, 0, 0, 0);
        #pragma unroll
        for (int r = 0; r < 4; ++r) {
            const float sc = hv - d[r];
            if (sc < mn[r]) { mn[r] = sc; mi[r] = eidx; }
        }
    }
    #pragma unroll
    for (int m = 1; m < 16; m <<= 1) {
        #pragma unroll
        for (int r = 0; r < 4; ++r) {
            const float ov = __shfl_xor(mn[r], m);
            const int   oi = __shfl_xor(mi[r], m);
            if (ov < mn[r] || (ov == mn[r] && oi < mi[r])) { mn[r] = ov; mi[r] = oi; }
        }
    }
    if (l15 == 0) {
        #pragma unroll
        for (int r = 0; r < 4; ++r) {
            pscore[chunk * MPAD + p0 + q * 4 + r] = mn[r];
            pcidx [chunk * MPAD + p0 + q * 4 + r] = mi[r];
        }
    }
}

// ---------------- Kernel 2: fp8 MFMA GEMM, BK=32, triple-buffered counted-vmcnt,
//                  (256,5) r16-proven; codes merged inline from chunk partials ----
__global__ __launch_bounds__(256, 5) void logits_mfma(
    const unsigned char* __restrict__ encF8, const unsigned char* __restrict__ tnoF8,
    const float* __restrict__ pscore, const int* __restrict__ pcidx,
    float* __restrict__ pm, float* __restrict__ ps, int* __restrict__ pidx,
    float* __restrict__ tgtlog)
{
    __shared__ __align__(16) unsigned char As3[3][128 * 32];   // 12 KB
    __shared__ __align__(16) unsigned char Bs3[3][128 * 32];   // 12 KB
    __shared__ float redM[2][128];
    __shared__ float redS[2][128];
    __shared__ int   redI[2][128];

    const int tid  = threadIdx.x;
    const int lane = tid & 63;
    const int wave = tid >> 6;
    const int wr = wave >> 1, wc = wave & 1;

    // XCD-aware mapping, mt-fastest within each XCD chunk
    const int bid = blockIdx.x;
    const int xcd = bid & 7;
    const int idx = bid >> 3;
    const int mt  = xcd * 8 + (idx & 7);
    const int vt  = idx >> 3;
    const int m0 = mt * 128, n0 = vt * 128;

    // staging: rows of 32 fp8 (32B, 2 chunks of 16B); one gl_lds = 32 rows (1KB) per matrix.
    // involution: LDS slot s of row r holds global chunk s ^ ((r>>2)&1)  -> 2-way banks (free)
    const int srow = lane >> 1;                              // 0..31 row within wave's 32-row band
    const int gcB  = ((lane & 1) ^ ((lane >> 3) & 1)) * 16;  // pre-swizzled source chunk (bytes)
    const size_t abase0 = (size_t)(m0 + wave * 32 + srow) * ENCD + gcB;
    const size_t bbase0 = (size_t)(n0 + wave * 32 + srow) * ENCD + gcB;

#define STAGE(t, buf)                                                                        \
    {                                                                                        \
        const int k0s = (t) * 32;                                                            \
        gl_lds16(encF8 + abase0 + k0s, &As3[buf][(wave * 32) * 32]);                         \
        gl_lds16(tnoF8 + bbase0 + k0s, &Bs3[buf][(wave * 32) * 32]);                         \
    }

    f32x4 acc[4][4];
    #pragma unroll
    for (int i = 0; i < 4; ++i)
        #pragma unroll
        for (int j = 0; j < 4; ++j)
            acc[i][j] = (f32x4){0.f, 0.f, 0.f, 0.f};

    const int l15 = lane & 15, q = lane >> 4;
    // read: lane needs bytes [q*8, q*8+8) of its 32B row; chunk = q>>1 (XOR row swizzle), half = q&1
    const int rsw = (l15 >> 2) & 1;
    const int co  = (((q >> 1) ^ rsw) * 16) + (q & 1) * 8;

    STAGE(0, 0);
    STAGE(1, 1);

    #pragma unroll
    for (int t = 0; t < 16; ++t) {
        if (t < 15) { asm volatile("s_waitcnt vmcnt(2)" ::: "memory"); }
        else        { asm volatile("s_waitcnt vmcnt(0)" ::: "memory"); }
        __builtin_amdgcn_s_barrier();
        __builtin_amdgcn_sched_barrier(0);
        if (t + 2 < 16) {
            const int nb = (t + 2) % 3;
            STAGE(t + 2, nb);
        }
        const unsigned char* Ab = As3[t % 3];
        const unsigned char* Bb = Bs3[t % 3];
        long a[4], b[4];
        #pragma unroll
        for (int mi = 0; mi < 4; ++mi)
            a[mi] = *(const long*)&Ab[(wr * 64 + mi * 16 + l15) * 32 + co];
        #pragma unroll
        for (int ni = 0; ni < 4; ++ni)
            b[ni] = *(const long*)&Bb[(wc * 64 + ni * 16 + l15) * 32 + co];
        __builtin_amdgcn_s_setprio(1);
        #pragma unroll
        for (int mi = 0; mi < 4; ++mi)
            #pragma unroll
            for (int ni = 0; ni < 4; ++ni)
                acc[mi][ni] = __builtin_amdgcn_mfma_f32_16x16x32_fp8_fp8(a[mi], b[ni], acc[mi][ni], 0, 0, 0);
        __builtin_amdgcn_s_setprio(0);
    }
#undef STAGE

    // undo the tno x16 scaling (exact pow2)
    #pragma unroll
    for (int mi = 0; mi < 4; ++mi)
        #pragma unroll
        for (int ni = 0; ni < 4; ++ni)
            acc[mi][ni] *= 0.0625f;

    // Epilogue: per-row partial max / first-argmax / sumexp over this block's 128 cols.
    #pragma unroll
    for (int mi = 0; mi < 4; ++mi) {
        #pragma unroll
        for (int r = 0; r < 4; ++r) {
            const int rl = wr * 64 + mi * 16 + q * 4 + r;   // local row 0..127
            float lm = -INFINITY; int li = 0;
            #pragma unroll
            for (int ni = 0; ni < 4; ++ni) {
                const float v = acc[mi][ni][r];
                const int col = wc * 64 + ni * 16 + l15;
                if (v > lm) { lm = v; li = col; }           // ascending col per lane
            }
            #pragma unroll
            for (int mk = 8; mk >= 1; mk >>= 1) {
                const float ov = __shfl_xor(lm, mk);
                const int   oi = __shfl_xor(li, mk);
                if (ov > lm || (ov == lm && oi < li)) { lm = ov; li = oi; }
            }
            float le = 0.f;
            #pragma unroll
            for (int ni = 0; ni < 4; ++ni) le += __expf(acc[mi][ni][r] - lm);
            #pragma unroll
            for (int mk = 8; mk >= 1; mk >>= 1) le += __shfl_xor(le, mk);

            if (l15 == 0) { redM[wc][rl] = lm; redS[wc][rl] = le; redI[wc][rl] = li; }

            const int mg = m0 + rl;
            if (mg < MROWS) {
                const int bb = mg / 511, tt = mg - bb * 511;
                const int tv = merge_code(pscore, pcidx, bb * NPOS + tt + 1);
                const int rel = tv - n0 - wc * 64;
                #pragma unroll
                for (int ni = 0; ni < 4; ++ni) {
                    if (rel >= ni * 16 && rel < ni * 16 + 16 && (rel & 15) == l15)
                        tgtlog[mg] = acc[mi][ni][r];
                }
            }
        }
    }
    __syncthreads();
    if (tid < 128) {
        const int rl = tid;
        const int mg = m0 + rl;
        if (mg < MROWS) {
            const float mA = redM[0][rl], mB = redM[1][rl];
            const int   iA = redI[0][rl], iB = redI[1][rl];
            float gm; int gi;
            if (mB > mA || (mB == mA && iB + 64 < iA)) { gm = mB; gi = 64 + iB; } else { gm = mA; gi = iA; }
            const float S = redS[0][rl] * __expf(mA - gm) + redS[1][rl] * __expf(mB - gm);
            pm[(size_t)vt * MPAD + mg]   = gm;
            ps[(size_t)vt * MPAD + mg]   = S;
            pidx[(size_t)vt * MPAD + mg] = n0 + gi;
        }
    }
}

// ---------------- Kernel 3: combine per-row + block reduce + ticketed last-block finalize ----
__global__ __launch_bounds__(256) void combine_kernel(
    const float* __restrict__ pm, const float* __restrict__ ps,
    const int* __restrict__ pidx, const float* __restrict__ tgtlog,
    const float* __restrict__ pscore, const int* __restrict__ pcidx,
    const int* __restrict__ lens,
    int* __restrict__ presence, int* __restrict__ sctrl,
    float* __restrict__ out)
{
    float* partials = (float*)(sctrl + 64);   // 32 blocks x 3 floats
    const int tid = threadIdx.x;
    const int g = blockIdx.x * 256 + tid;
    float nll = 0.f, corr = 0.f, mfv = 0.f;
    if (g < MROWS) {
        float gm = -INFINITY; int gi = 0;
        #pragma unroll 8
        for (int nt = 0; nt < NVT; ++nt) {
            const float v = pm[(size_t)nt * MPAD + g];
            if (v > gm) { gm = v; gi = pidx[(size_t)nt * MPAD + g]; }
        }
        float S = 0.f;
        #pragma unroll 8
        for (int nt = 0; nt < NVT; ++nt) S += ps[(size_t)nt * MPAD + g] * __expf(pm[(size_t)nt * MPAD + g] - gm);
        const float lse = gm + logf(S);
        const int b = g / 511, t = g - b * 511;
        const int tv = merge_code(pscore, pcidx, b * NPOS + t + 1);
        const int L = lens[b];
        const int s = t + 1;
        const bool mf = (s < (L / 4)) && (4 * s + 3 < L);
        if (mf) {
            nll = lse - tgtlog[g];
            corr = (gi == tv) ? 1.f : 0.f;
            mfv = 1.f;
            presence[tv] = 1;     // plain store; ordered before this block's fence below
        }
    }
    __shared__ float s0[256], s1[256], s2[256];
    __shared__ int shp[256];
    __shared__ int isLast;
    s0[tid] = nll; s1[tid] = corr; s2[tid] = mfv;
    __syncthreads();
    for (int st = 128; st > 0; st >>= 1) {
        if (tid < st) { s0[tid] += s0[tid + st]; s1[tid] += s1[tid + st]; s2[tid] += s2[tid + st]; }
        __syncthreads();
    }
    if (tid == 0) {
        partials[blockIdx.x * 3 + 0] = s0[0];
        partials[blockIdx.x * 3 + 1] = s1[0];
        partials[blockIdx.x * 3 + 2] = s2[0];
        __threadfence();
        isLast = (atomicAdd(&sctrl[0], 1) == 31);
    }
    __syncthreads();
    if (!isLast) return;
    __threadfence();

    float tn = 0.f, tc = 0.f, tm = 0.f;
    if (tid == 0) {
        for (int i = 0; i < 32; ++i) {
            tn += partials[i * 3 + 0];
            tc += partials[i * 3 + 1];
            tm += partials[i * 3 + 2];
        }
    }
    int pp = 0;
    for (int v = tid; v < NEMB; v += 256) pp += presence[v];
    shp[tid] = pp;
    __syncthreads();
    for (int st = 128; st > 0; st >>= 1) {
        if (tid < st) shp[tid] += shp[tid + st];
        __syncthreads();
    }
    if (tid == 0) {
        out[0] = tn / tm;
        out[1] = tc / tm;
        out[2] = tm;
        out[3] = (float)shp[0];
    }
}

extern "C" void kernel_launch(void* const* d_in, const int* in_sizes, int n_in,
                              void* d_out, int out_size, void* d_ws, size_t ws_size,
                              hipStream_t stream) {
    const float* feats = (const float*)d_in[0];
    const int*   lens  = (const int*)d_in[1];
    const float* enc   = (const float*)d_in[2];
    const float* proj  = (const float*)d_in[3];
    const float* emb   = (const float*)d_in[4];
    const float* tno   = (const float*)d_in[5];
    float* out = (float*)d_out;

    int* presence       = (int*)d_ws;                        // 8192
    float* pm           = (float*)(presence + MPAD);         // 64*8192
    float* ps           = pm + (size_t)NVT * MPAD;           // 64*8192
    int* pidx           = (int*)(ps + (size_t)NVT * MPAD);   // 64*8192
    float* tgtlog       = (float*)(pidx + (size_t)NVT * MPAD); // 8192
    float* pscore       = tgtlog + MPAD;                     // 4*8192
    int*   pcidx        = (int*)(pscore + 4 * MPAD);         // 4*8192
    float* h2           = (float*)(pcidx + 4 * MPAD);        // 8192
    int*   sctrl        = (int*)(h2 + MPAD);                 // 64 ctrl + 96 partials
    unsigned short* ynB  = (unsigned short*)(sctrl + 160);   // 8192*32 bf16
    unsigned short* embB = ynB + (size_t)MPAD * 32;          // 8192*32 bf16
    unsigned char* encF8 = (unsigned char*)(embB + (size_t)MPAD * 32); // 8192*512 bytes
    unsigned char* tnoF8 = encF8 + (size_t)MPAD * ENCD;      // 8192*512 bytes

    hipLaunchKernelGGL(prep_kernel, dim3(2080), dim3(256), 0, stream,
                       feats, proj, emb, enc, tno, ynB, embB, h2, presence, sctrl, encF8, tnoF8);
    hipLaunchKernelGGL(codes_mfma, dim3(512), dim3(256), 0, stream, ynB, embB, h2, pscore, pcidx);
    hipLaunchKernelGGL(logits_mfma, dim3(64 * 64), dim3(256), 0, stream, encF8, tnoF8, pscore, pcidx, pm, ps, pidx, tgtlog);
    hipLaunchKernelGGL(combine_kernel, dim3(32), dim3(256), 0, stream,
                       pm, ps, pidx, tgtlog, pscore, pcidx, lens, presence, sctrl, out);
}

// Round 21
// 209.051 us; speedup vs baseline: 1.1126x; 1.1126x over previous
//
#include <hip/hip_runtime.h>
#include <math.h>

typedef __attribute__((ext_vector_type(4))) float f32x4;
typedef __attribute__((ext_vector_type(8))) short bf16x8;

// Problem constants
#define NB 16
#define NT 2048
#define NMEL 80
#define NPOS 512          // stacked positions per batch
#define EDIM 16
#define NEMB 8192
#define ENCD 512
#define MROWS (NB*511)    // 8176 logit rows
#define MPAD 8192
#define NVT 64            // 8192 / 128 col tiles

__device__ __forceinline__ unsigned short f2bf(float x) {
    union { float f; unsigned u; } v; v.f = x;
    unsigned r = v.u + 0x7fffu + ((v.u >> 16) & 1u);
    return (unsigned short)(r >> 16);
}

__device__ __forceinline__ void gl_lds16(const void* gsrc, void* lds) {
    __builtin_amdgcn_global_load_lds(
        (const __attribute__((address_space(1))) unsigned int*)gsrc,
        (__attribute__((address_space(3))) unsigned int*)lds,
        16, 0, 0);
}

// ---------------- Kernel 1: prep ----------------
// blocks 0..511   : LN+proj+normalize -> ynB bf16 [8192][32] (K-padded); zero presence/sctrl
// blocks 512..1023: enc->fp8
// blocks 1024..2047: tno->fp8 transpose x16
// blocks 2048..2079: emb -> embB bf16 [8192][32] (K-padded) + h2 f32 (exact)
__global__ __launch_bounds__(256) void prep_kernel(
    const float* __restrict__ feats, const float* __restrict__ proj,
    const float* __restrict__ emb, const float* __restrict__ enc,
    const float* __restrict__ tno,
    unsigned short* __restrict__ ynB, unsigned short* __restrict__ embB,
    float* __restrict__ h2, int* __restrict__ presence, int* __restrict__ sctrl,
    unsigned char* __restrict__ encF8, unsigned char* __restrict__ tnoF8)
{
    __shared__ float tileT[32][33];         // tno transpose staging
    const int bid = blockIdx.x;
    const int tid = threadIdx.x;

    if (bid < 512) {
        // ---- LN path: 16 positions per block, 4 per wave ----
        const int lane = tid & 63;
        const int wave = tid >> 6;
        const int gbase = bid * 16 + wave * 4;
        if (bid < 32) presence[bid * 256 + tid] = 0;
        if (bid == 32 && tid < 160) sctrl[tid] = 0;   // ticket + partials

        float yn[4][EDIM];
        #pragma unroll
        for (int pi = 0; pi < 4; ++pi) {
            const int g = gbase + pi;
            const int b = g >> 9;
            const int i = g & 511;
            float xv[5];
            float s = 0.f, sq = 0.f;
            #pragma unroll
            for (int qq = 0; qq < 5; ++qq) {
                const int d = lane + 64 * qq;
                const int j = d / 80, k = d - j * 80;
                const float v = feats[((b * NT) + (i * 4 + j)) * NMEL + k];
                xv[qq] = v; s += v; sq += v * v;
            }
            for (int m = 1; m < 64; m <<= 1) { s += __shfl_xor(s, m); sq += __shfl_xor(sq, m); }
            const float mean = s * (1.0f / 320.0f);
            const float var  = sq * (1.0f / 320.0f) - mean * mean;
            const float rstd = rsqrtf(var + 1e-6f);
            float acc[EDIM];
            #pragma unroll
            for (int e = 0; e < EDIM; ++e) acc[e] = 0.f;
            #pragma unroll
            for (int qq = 0; qq < 5; ++qq) {
                const int d = lane + 64 * qq;
                const float xn = (xv[qq] - mean) * rstd;
                #pragma unroll
                for (int e = 0; e < EDIM; ++e) acc[e] += xn * proj[d * EDIM + e];
            }
            for (int m = 1; m < 64; m <<= 1) {
                #pragma unroll
                for (int e = 0; e < EDIM; ++e) acc[e] += __shfl_xor(acc[e], m);
            }
            float nsq = 0.f;
            #pragma unroll
            for (int e = 0; e < EDIM; ++e) nsq += acc[e] * acc[e];
            const float inv = 1.0f / (sqrtf(nsq) + 1e-8f);
            #pragma unroll
            for (int e = 0; e < EDIM; ++e) yn[pi][e] = acc[e] * inv;
        }
        // all lanes hold the full yn after butterfly; lanes 0..3 write their position
        #pragma unroll
        for (int pi = 0; pi < 4; ++pi) {
            if (lane == pi) {
                unsigned short* dst = &ynB[(size_t)(gbase + pi) * 32];
                #pragma unroll
                for (int e = 0; e < EDIM; ++e) dst[e] = f2bf(yn[pi][e]);
                #pragma unroll
                for (int e = EDIM; e < 32; ++e) dst[e] = 0;
            }
        }
    } else if (bid < 1024) {
        // ---- enc f32 -> encF8 e4m3 [8192][512] bytes, padded rows zero ----
        const int bid2 = bid - 512;          // 0..511 -> 16 rows each
        const int lane = tid & 63;
        #pragma unroll
        for (int pass = 0; pass < 4; ++pass) {
            const int m = bid2 * 16 + pass * 4 + (tid >> 6);
            const int d = lane * 8;
            uint2 o = make_uint2(0u, 0u);
            if (m < MROWS) {
                const int b = m / 511, t = m - b * 511;
                const float4 f0 = *(const float4*)&enc[((size_t)(b * 512 + t)) * ENCD + d];
                const float4 f1 = *(const float4*)&enc[((size_t)(b * 512 + t)) * ENCD + d + 4];
                int w0 = __builtin_amdgcn_cvt_pk_fp8_f32(f0.x, f0.y, 0, false);
                w0     = __builtin_amdgcn_cvt_pk_fp8_f32(f0.z, f0.w, w0, true);
                int w1 = __builtin_amdgcn_cvt_pk_fp8_f32(f1.x, f1.y, 0, false);
                w1     = __builtin_amdgcn_cvt_pk_fp8_f32(f1.z, f1.w, w1, true);
                o.x = (unsigned)w0; o.y = (unsigned)w1;
            }
            *(uint2*)&encF8[(size_t)m * ENCD + d] = o;
        }
    } else if (bid < 2048) {
        // ---- tno f32 [512][8192] -> tnoF8 e4m3 [8192][512] bytes, scaled x16 ----
        const int bid2 = bid - 1024;         // 0..1023 -> 4 tiles each
        const int tx = tid & 31, ty = tid >> 5;   // 32 x 8 loaders
        const int np = tid >> 3, kc = tid & 7;    // 32 n-rows x 8 k-quads writers
        #pragma unroll
        for (int it = 0; it < 4; ++it) {
            const int tile = bid2 * 4 + it;       // 0..4095
            const int n0 = (tile & 255) * 32;
            const int k0 = (tile >> 8) * 32;
            __syncthreads();
            #pragma unroll
            for (int i = 0; i < 4; ++i)
                tileT[ty + 8 * i][tx] = tno[(size_t)(k0 + ty + 8 * i) * NEMB + n0 + tx];
            __syncthreads();
            const float t0 = 16.0f * tileT[kc * 4 + 0][np];
            const float t1 = 16.0f * tileT[kc * 4 + 1][np];
            const float t2 = 16.0f * tileT[kc * 4 + 2][np];
            const float t3 = 16.0f * tileT[kc * 4 + 3][np];
            int w = __builtin_amdgcn_cvt_pk_fp8_f32(t0, t1, 0, false);
            w     = __builtin_amdgcn_cvt_pk_fp8_f32(t2, t3, w, true);
            ((unsigned*)tnoF8)[(size_t)(n0 + np) * (ENCD / 4) + (k0 >> 2) + kc] = (unsigned)w;
        }
    } else {
        // ---- emb f32 [8192][16] -> embB bf16 [8192][32] (K-pad zeros) + h2 exact ----
        const int row = (bid - 2048) * 256 + tid;   // one row per thread
        const float* ep = &emb[(size_t)row * EDIM];
        const float4 e0 = *(const float4*)&ep[0];
        const float4 e1 = *(const float4*)&ep[4];
        const float4 e2v = *(const float4*)&ep[8];
        const float4 e3 = *(const float4*)&ep[12];
        const float e2 = e0.x*e0.x + e0.y*e0.y + e0.z*e0.z + e0.w*e0.w
                       + e1.x*e1.x + e1.y*e1.y + e1.z*e1.z + e1.w*e1.w
                       + e2v.x*e2v.x + e2v.y*e2v.y + e2v.z*e2v.z + e2v.w*e2v.w
                       + e3.x*e3.x + e3.y*e3.y + e3.z*e3.z + e3.w*e3.w;
        h2[row] = 0.5f * e2;
        unsigned short* dst = &embB[(size_t)row * 32];
        dst[0]  = f2bf(e0.x); dst[1]  = f2bf(e0.y); dst[2]  = f2bf(e0.z); dst[3]  = f2bf(e0.w);
        dst[4]  = f2bf(e1.x); dst[5]  = f2bf(e1.y); dst[6]  = f2bf(e1.z); dst[7]  = f2bf(e1.w);
        dst[8]  = f2bf(e2v.x); dst[9]  = f2bf(e2v.y); dst[10] = f2bf(e2v.z); dst[11] = f2bf(e2v.w);
        dst[12] = f2bf(e3.x); dst[13] = f2bf(e3.y); dst[14] = f2bf(e3.z); dst[15] = f2bf(e3.w);
        #pragma unroll
        for (int e = EDIM; e < 32; ++e) dst[e] = 0;
    }
}

// ---------------- Kernel 1b: MFMA argmin scan (pos-group x emb-chunk partials) ----------------
__global__ __launch_bounds__(256) void codes_mfma(
    const unsigned short* __restrict__ ynB, const unsigned short* __restrict__ embB,
    const float* __restrict__ h2,
    float* __restrict__ pscore, int* __restrict__ pcidx)
{
    const int tid = threadIdx.x;
    const int lane = tid & 63;
    const int wave = tid >> 6;
    const int pgrp  = blockIdx.x >> 2;   // 0..127 -> 64 positions
    const int chunk = blockIdx.x & 3;    // 0..3 -> 2048 embeddings
    const int p0 = pgrp * 64 + wave * 16;
    const int l15 = lane & 15, q = lane >> 4;

    const bf16x8 a = *(const bf16x8*)&ynB[(size_t)(p0 + l15) * 32 + q * 8];

    float mn[4]; int mi[4];
    #pragma unroll
    for (int r = 0; r < 4; ++r) { mn[r] = INFINITY; mi[r] = 0x7fffffff; }

    const int e0 = chunk * 2048;
    #pragma unroll 4
    for (int g = 0; g < 128; ++g) {
        const int eidx = e0 + g * 16 + l15;
        const bf16x8 b = *(const bf16x8*)&embB[(size_t)eidx * 32 + q * 8];
        const float hv = h2[eidx];
        f32x4 d = __builtin_amdgcn_mfma_f32_16x16x32_bf16(a, b, (f32x4){0.f, 0.f, 0.f, 0.f}, 0, 0, 0);
        #pragma unroll
        for (int r = 0; r < 4; ++r) {
            const float sc = hv - d[r];
            if (sc < mn[r]) { mn[r] = sc; mi[r] = eidx; }
        }
    }
    #pragma unroll
    for (int m = 1; m < 16; m <<= 1) {
        #pragma unroll
        for (int r = 0; r < 4; ++r) {
            const float ov = __shfl_xor(mn[r], m);
            const int   oi = __shfl_xor(mi[r], m);
            if (ov < mn[r] || (ov == mn[r] && oi < mi[r])) { mn[r] = ov; mi[r] = oi; }
        }
    }
    if (l15 == 0) {
        #pragma unroll
        for (int r = 0; r < 4; ++r) {
            pscore[chunk * MPAD + p0 + q * 4 + r] = mn[r];
            pcidx [chunk * MPAD + p0 + q * 4 + r] = mi[r];
        }
    }
}

// ---------------- Kernel 1c: merge 4 chunk partials -> codes ----------------
__global__ __launch_bounds__(256) void codes_merge(
    const float* __restrict__ pscore, const int* __restrict__ pcidx,
    int* __restrict__ codes)
{
    const int g = blockIdx.x * 256 + threadIdx.x;   // 0..8191
    float m = INFINITY; int mi = 0x7fffffff;
    #pragma unroll
    for (int c = 0; c < 4; ++c) {
        const float s = pscore[c * MPAD + g];
        const int  ix = pcidx [c * MPAD + g];
        if (s < m || (s == m && ix < mi)) { m = s; mi = ix; }
    }
    codes[g] = mi;
}

// ---------------- Kernel 2: fp8 MFMA GEMM, BK=32, triple-buffered counted-vmcnt,
//                  (256,5) r16-proven; reads materialized codes[] ----
__global__ __launch_bounds__(256, 5) void logits_mfma(
    const unsigned char* __restrict__ encF8, const unsigned char* __restrict__ tnoF8,
    const int* __restrict__ codes,
    float* __restrict__ pm, float* __restrict__ ps, int* __restrict__ pidx,
    float* __restrict__ tgtlog)
{
    __shared__ __align__(16) unsigned char As3[3][128 * 32];   // 12 KB
    __shared__ __align__(16) unsigned char Bs3[3][128 * 32];   // 12 KB
    __shared__ float redM[2][128];
    __shared__ float redS[2][128];
    __shared__ int   redI[2][128];

    const int tid  = threadIdx.x;
    const int lane = tid & 63;
    const int wave = tid >> 6;
    const int wr = wave >> 1, wc = wave & 1;

    // XCD-aware mapping, mt-fastest within each XCD chunk
    const int bid = blockIdx.x;
    const int xcd = bid & 7;
    const int idx = bid >> 3;
    const int mt  = xcd * 8 + (idx & 7);
    const int vt  = idx >> 3;
    const int m0 = mt * 128, n0 = vt * 128;

    // staging: rows of 32 fp8 (32B, 2 chunks of 16B); one gl_lds = 32 rows (1KB) per matrix.
    // involution: LDS slot s of row r holds global chunk s ^ ((r>>2)&1)  -> 2-way banks (free)
    const int srow = lane >> 1;                              // 0..31 row within wave's 32-row band
    const int gcB  = ((lane & 1) ^ ((lane >> 3) & 1)) * 16;  // pre-swizzled source chunk (bytes)
    const size_t abase0 = (size_t)(m0 + wave * 32 + srow) * ENCD + gcB;
    const size_t bbase0 = (size_t)(n0 + wave * 32 + srow) * ENCD + gcB;

#define STAGE(t, buf)                                                                        \
    {                                                                                        \
        const int k0s = (t) * 32;                                                            \
        gl_lds16(encF8 + abase0 + k0s, &As3[buf][(wave * 32) * 32]);                         \
        gl_lds16(tnoF8 + bbase0 + k0s, &Bs3[buf][(wave * 32) * 32]);                         \
    }

    f32x4 acc[4][4];
    #pragma unroll
    for (int i = 0; i < 4; ++i)
        #pragma unroll
        for (int j = 0; j < 4; ++j)
            acc[i][j] = (f32x4){0.f, 0.f, 0.f, 0.f};

    const int l15 = lane & 15, q = lane >> 4;
    // read: lane needs bytes [q*8, q*8+8) of its 32B row; chunk = q>>1 (XOR row swizzle), half = q&1
    const int rsw = (l15 >> 2) & 1;
    const int co  = (((q >> 1) ^ rsw) * 16) + (q & 1) * 8;

    STAGE(0, 0);
    STAGE(1, 1);

    #pragma unroll
    for (int t = 0; t < 16; ++t) {
        if (t < 15) { asm volatile("s_waitcnt vmcnt(2)" ::: "memory"); }
        else        { asm volatile("s_waitcnt vmcnt(0)" ::: "memory"); }
        __builtin_amdgcn_s_barrier();
        __builtin_amdgcn_sched_barrier(0);
        if (t + 2 < 16) {
            const int nb = (t + 2) % 3;
            STAGE(t + 2, nb);
        }
        const unsigned char* Ab = As3[t % 3];
        const unsigned char* Bb = Bs3[t % 3];
        long a[4], b[4];
        #pragma unroll
        for (int mi = 0; mi < 4; ++mi)
            a[mi] = *(const long*)&Ab[(wr * 64 + mi * 16 + l15) * 32 + co];
        #pragma unroll
        for (int ni = 0; ni < 4; ++ni)
            b[ni] = *(const long*)&Bb[(wc * 64 + ni * 16 + l15) * 32 + co];
        __builtin_amdgcn_s_setprio(1);
        #pragma unroll
        for (int mi = 0; mi < 4; ++mi)
            #pragma unroll
            for (int ni = 0; ni < 4; ++ni)
                acc[mi][ni] = __builtin_amdgcn_mfma_f32_16x16x32_fp8_fp8(a[mi], b[ni], acc[mi][ni], 0, 0, 0);
        __builtin_amdgcn_s_setprio(0);
    }
#undef STAGE

    // undo the tno x16 scaling (exact pow2)
    #pragma unroll
    for (int mi = 0; mi < 4; ++mi)
        #pragma unroll
        for (int ni = 0; ni < 4; ++ni)
            acc[mi][ni] *= 0.0625f;

    // Epilogue: per-row partial max / first-argmax / sumexp over this block's 128 cols.
    #pragma unroll
    for (int mi = 0; mi < 4; ++mi) {
        #pragma unroll
        for (int r = 0; r < 4; ++r) {
            const int rl = wr * 64 + mi * 16 + q * 4 + r;   // local row 0..127
            float lm = -INFINITY; int li = 0;
            #pragma unroll
            for (int ni = 0; ni < 4; ++ni) {
                const float v = acc[mi][ni][r];
                const int col = wc * 64 + ni * 16 + l15;
                if (v > lm) { lm = v; li = col; }           // ascending col per lane
            }
            #pragma unroll
            for (int mk = 8; mk >= 1; mk >>= 1) {
                const float ov = __shfl_xor(lm, mk);
                const int   oi = __shfl_xor(li, mk);
                if (ov > lm || (ov == lm && oi < li)) { lm = ov; li = oi; }
            }
            float le = 0.f;
            #pragma unroll
            for (int ni = 0; ni < 4; ++ni) le += __expf(acc[mi][ni][r] - lm);
            #pragma unroll
            for (int mk = 8; mk >= 1; mk >>= 1) le += __shfl_xor(le, mk);

            if (l15 == 0) { redM[wc][rl] = lm; redS[wc][rl] = le; redI[wc][rl] = li; }

            const int mg = m0 + rl;
            if (mg < MROWS) {
                const int bb = mg / 511, tt = mg - bb * 511;
                const int tv = codes[bb * NPOS + tt + 1];
                const int rel = tv - n0 - wc * 64;
                #pragma unroll
                for (int ni = 0; ni < 4; ++ni) {
                    if (rel >= ni * 16 && rel < ni * 16 + 16 && (rel & 15) == l15)
                        tgtlog[mg] = acc[mi][ni][r];
                }
            }
        }
    }
    __syncthreads();
    if (tid < 128) {
        const int rl = tid;
        const int mg = m0 + rl;
        if (mg < MROWS) {
            const float mA = redM[0][rl], mB = redM[1][rl];
            const int   iA = redI[0][rl], iB = redI[1][rl];
            float gm; int gi;
            if (mB > mA || (mB == mA && iB + 64 < iA)) { gm = mB; gi = 64 + iB; } else { gm = mA; gi = iA; }
            const float S = redS[0][rl] * __expf(mA - gm) + redS[1][rl] * __expf(mB - gm);
            pm[(size_t)vt * MPAD + mg]   = gm;
            ps[(size_t)vt * MPAD + mg]   = S;
            pidx[(size_t)vt * MPAD + mg] = n0 + gi;
        }
    }
}

// ---------------- Kernel 3: combine per-row + block reduce + ticketed last-block finalize ----
__global__ __launch_bounds__(256) void combine_kernel(
    const float* __restrict__ pm, const float* __restrict__ ps,
    const int* __restrict__ pidx, const float* __restrict__ tgtlog,
    const int* __restrict__ codes, const int* __restrict__ lens,
    int* __restrict__ presence, int* __restrict__ sctrl,
    float* __restrict__ out)
{
    float* partials = (float*)(sctrl + 64);   // 32 blocks x 3 floats
    const int tid = threadIdx.x;
    const int g = blockIdx.x * 256 + tid;
    float nll = 0.f, corr = 0.f, mfv = 0.f;
    if (g < MROWS) {
        float gm = -INFINITY; int gi = 0;
        #pragma unroll 8
        for (int nt = 0; nt < NVT; ++nt) {
            const float v = pm[(size_t)nt * MPAD + g];
            if (v > gm) { gm = v; gi = pidx[(size_t)nt * MPAD + g]; }
        }
        float S = 0.f;
        #pragma unroll 8
        for (int nt = 0; nt < NVT; ++nt) S += ps[(size_t)nt * MPAD + g] * __expf(pm[(size_t)nt * MPAD + g] - gm);
        const float lse = gm + logf(S);
        const int b = g / 511, t = g - b * 511;
        const int tv = codes[b * NPOS + t + 1];
        const int L = lens[b];
        const int s = t + 1;
        const bool mf = (s < (L / 4)) && (4 * s + 3 < L);
        if (mf) {
            nll = lse - tgtlog[g];
            corr = (gi == tv) ? 1.f : 0.f;
            mfv = 1.f;
            presence[tv] = 1;     // plain store; ordered before this block's fence below
        }
    }
    __shared__ float s0[256], s1[256], s2[256];
    __shared__ int shp[256];
    __shared__ int isLast;
    s0[tid] = nll; s1[tid] = corr; s2[tid] = mfv;
    __syncthreads();
    for (int st = 128; st > 0; st >>= 1) {
        if (tid < st) { s0[tid] += s0[tid + st]; s1[tid] += s1[tid + st]; s2[tid] += s2[tid + st]; }
        __syncthreads();
    }
    if (tid == 0) {
        partials[blockIdx.x * 3 + 0] = s0[0];
        partials[blockIdx.x * 3 + 1] = s1[0];
        partials[blockIdx.x * 3 + 2] = s2[0];
        __threadfence();
        isLast = (atomicAdd(&sctrl[0], 1) == 31);
    }
    __syncthreads();
    if (!isLast) return;
    __threadfence();

    float tn = 0.f, tc = 0.f, tm = 0.f;
    if (tid == 0) {
        for (int i = 0; i < 32; ++i) {
            tn += partials[i * 3 + 0];
            tc += partials[i * 3 + 1];
            tm += partials[i * 3 + 2];
        }
    }
    int pp = 0;
    for (int v = tid; v < NEMB; v += 256) pp += presence[v];
    shp[tid] = pp;
    __syncthreads();
    for (int st = 128; st > 0; st >>= 1) {
        if (tid < st) shp[tid] += shp[tid + st];
        __syncthreads();
    }
    if (tid == 0) {
        out[0] = tn / tm;
        out[1] = tc / tm;
        out[2] = tm;
        out[3] = (float)shp[0];
    }
}

extern "C" void kernel_launch(void* const* d_in, const int* in_sizes, int n_in,
                              void* d_out, int out_size, void* d_ws, size_t ws_size,
                              hipStream_t stream) {
    const float* feats = (const float*)d_in[0];
    const int*   lens  = (const int*)d_in[1];
    const float* enc   = (const float*)d_in[2];
    const float* proj  = (const float*)d_in[3];
    const float* emb   = (const float*)d_in[4];
    const float* tno   = (const float*)d_in[5];
    float* out = (float*)d_out;

    int* codes          = (int*)d_ws;                        // 8192
    int* presence       = codes + MPAD;                      // 8192
    float* pm           = (float*)(presence + MPAD);         // 64*8192
    float* ps           = pm + (size_t)NVT * MPAD;           // 64*8192
    int* pidx           = (int*)(ps + (size_t)NVT * MPAD);   // 64*8192
    float* tgtlog       = (float*)(pidx + (size_t)NVT * MPAD); // 8192
    float* pscore       = tgtlog + MPAD;                     // 4*8192
    int*   pcidx        = (int*)(pscore + 4 * MPAD);         // 4*8192
    float* h2           = (float*)(pcidx + 4 * MPAD);        // 8192
    int*   sctrl        = (int*)(h2 + MPAD);                 // 64 ctrl + 96 partials
    unsigned short* ynB  = (unsigned short*)(sctrl + 160);   // 8192*32 bf16
    unsigned short* embB = ynB + (size_t)MPAD * 32;          // 8192*32 bf16
    unsigned char* encF8 = (unsigned char*)(embB + (size_t)MPAD * 32); // 8192*512 bytes
    unsigned char* tnoF8 = encF8 + (size_t)MPAD * ENCD;      // 8192*512 bytes

    hipLaunchKernelGGL(prep_kernel, dim3(2080), dim3(256), 0, stream,
                       feats, proj, emb, enc, tno, ynB, embB, h2, presence, sctrl, encF8, tnoF8);
    hipLaunchKernelGGL(codes_mfma, dim3(512), dim3(256), 0, stream, ynB, embB, h2, pscore, pcidx);
    hipLaunchKernelGGL(codes_merge, dim3(32), dim3(256), 0, stream, pscore, pcidx, codes);
    hipLaunchKernelGGL(logits_mfma, dim3(64 * 64), dim3(256), 0, stream, encF8, tnoF8, codes, pm, ps, pidx, tgtlog);
    hipLaunchKernelGGL(combine_kernel, dim3(32), dim3(256), 0, stream,
                       pm, ps, pidx, tgtlog, codes, lens, presence, sctrl, out);
}